// Round 2
// baseline (179.529 us; speedup 1.0000x reference)
//
#include <hip/hip_runtime.h>
#include <hip/hip_cooperative_groups.h>

// FSQ: z (4,16,256,64) fp32, bins (64,256) fp32 (uniform linspace(-1,1,256) per row).
// Outputs flat fp32: [loss(1), z_q(1048576), bin_indices_as_float(1048576)]
// loss = 2 * mean((z - zq)^2)   (commitment + BETA*codebook, BETA=1, identical forward)
//
// R1: 4 elems/thread, k*BLOCK stride (d = tid&63 per-thread constant -> one 1KB
//     bins row per thread), 1024 blocks. 72.2 -> 68.3 us.
// R2: fuse the two kernels into ONE cooperative launch. fsq_reduce was pure
//     dispatch latency (4KB of reads); grid.sync() + block-0 reduction removes
//     one launch and the inter-kernel gap. 1024 blocks x 4 waves = 4096 waves
//     (< 8192 co-resident) so cooperative occupancy is guaranteed.

#define N_ELEM (4 * 16 * 256 * 64) // 1048576
#define D_LAT 64
#define NBINS 256
#define BLOCK 256
#define VPT 4
#define CHUNK (BLOCK * VPT)   // 1024 elements per block
#define GRID (N_ELEM / CHUNK) // 1024

__global__ __launch_bounds__(BLOCK) void fsq_fused(const float* __restrict__ z,
                                                   const float* __restrict__ bins,
                                                   float* __restrict__ out,
                                                   float* __restrict__ partial) {
    const int tid = threadIdx.x;
    const int base = blockIdx.x * CHUNK + tid;
    // CHUNK and BLOCK are multiples of 64, so d = (base + k*BLOCK) & 63 == tid & 63:
    // each thread reads from exactly one 1KB bins row across all VPT elements.
    const float* __restrict__ brow = bins + (tid & (D_LAT - 1)) * NBINS;

    float s = 0.0f;
#pragma unroll
    for (int k = 0; k < VPT; ++k) {
        const int i = base + k * BLOCK;
        const float v = z[i];

        // Candidate nearest-bin index via uniform-spacing formula, clamped.
        float t = (v + 1.0f) * 127.5f;
        int j = (int)floorf(t + 0.5f);
        j = min(max(j, 0), NBINS - 1);

        // Refine with actual bin values; tie-break to LOWEST index (argmin semantics).
        int best = j;
        float bv = brow[j];
        float bd = fabsf(v - bv);
        if (j > 0) {
            float b0 = brow[j - 1];
            float d0 = fabsf(v - b0);
            if (d0 <= bd) { best = j - 1; bv = b0; bd = d0; } // <= : lower index wins tie
        }
        if (j + 1 < NBINS) {
            float b1 = brow[j + 1];
            float d1 = fabsf(v - b1);
            if (d1 < bd) { best = j + 1; bv = b1; bd = d1; } // strict < : lower index wins tie
        }

        out[1 + i] = bv;
        out[1 + N_ELEM + i] = (float)best;

        float diff = v - bv;
        s = fmaf(diff, diff, s);
    }

    // wave reduce, then 4-wave LDS combine -> one partial per block
#pragma unroll
    for (int off = 32; off > 0; off >>= 1) s += __shfl_down(s, off, 64);

    __shared__ float lds[BLOCK / 64];
    const int lane = tid & 63;
    const int wave = tid >> 6;
    if (lane == 0) lds[wave] = s;
    __syncthreads();
    if (tid == 0) partial[blockIdx.x] = lds[0] + lds[1] + lds[2] + lds[3];

    // grid-wide barrier, then block 0 folds the 1024 partials (deterministic tree)
    cooperative_groups::this_grid().sync();

    if (blockIdx.x == 0) {
        float t = partial[tid] + partial[tid + 256] + partial[tid + 512] + partial[tid + 768];
#pragma unroll
        for (int off = 32; off > 0; off >>= 1) t += __shfl_down(t, off, 64);

        __shared__ float lds2[BLOCK / 64];
        if (lane == 0) lds2[wave] = t;
        __syncthreads();
        if (tid == 0) out[0] = 2.0f * (lds2[0] + lds2[1] + lds2[2] + lds2[3]) / (float)N_ELEM;
    }
}

extern "C" void kernel_launch(void* const* d_in, const int* in_sizes, int n_in,
                              void* d_out, int out_size, void* d_ws, size_t ws_size,
                              hipStream_t stream) {
    const float* z = (const float*)d_in[0];
    const float* bins = (const float*)d_in[1];
    float* out = (float*)d_out;
    float* partial = (float*)d_ws; // 1024 floats, fully written before the grid sync

    void* args[] = {(void*)&z, (void*)&bins, (void*)&out, (void*)&partial};
    hipLaunchCooperativeKernel((const void*)fsq_fused, dim3(GRID), dim3(BLOCK), args, 0, stream);
}

// Round 3
// 87.962 us; speedup vs baseline: 2.0410x; 2.0410x over previous
//
#include <hip/hip_runtime.h>

// FSQ: z (4,16,256,64) fp32, bins (64,256) fp32 (uniform linspace(-1,1,256) per row).
// Outputs flat fp32: [loss(1), z_q(1048576), bin_indices_as_float(1048576)]
// loss = 2 * mean((z - zq)^2)   (commitment + BETA*codebook, BETA=1, identical forward)
//
// R1: 4 elems/thread, k*BLOCK stride (d = tid&63 per-thread constant -> one 1KB
//     bins row per thread), 1024 blocks + tiny reduce kernel. 72.2 -> 68.3 us.
// R2: cooperative grid.sync() fusion. FAILED: grid sync cost ~107 us (1024 blocks
//     spinning device-scope atomics across 8 non-coherent XCD L2s). 179.5 us.
// R3: single launch, NO grid barrier: last-writer signaling (rocPRIM lookback
//     idiom). Each block release-stores partial+magic flag; only block 0
//     acquire-spins on the 1024 flags then reduces. 1023 blocks exit instantly;
//     capacity 1024 blk x 4 waves = 4096 <= 8192 co-resident, so no starvation.

#define N_ELEM (4 * 16 * 256 * 64) // 1048576
#define D_LAT 64
#define NBINS 256
#define BLOCK 256
#define VPT 4
#define CHUNK (BLOCK * VPT)   // 1024 elements per block
#define GRID (N_ELEM / CHUNK) // 1024
#define FLAG_MAGIC 0x5AFEC0DEu // non-byte-repeating: cannot collide with fill poison

__global__ __launch_bounds__(BLOCK) void fsq_fused(const float* __restrict__ z,
                                                   const float* __restrict__ bins,
                                                   float* __restrict__ out,
                                                   float* __restrict__ partial,
                                                   unsigned int* __restrict__ flags) {
    const int tid = threadIdx.x;
    const int base = blockIdx.x * CHUNK + tid;
    // CHUNK and BLOCK are multiples of 64, so d = (base + k*BLOCK) & 63 == tid & 63:
    // each thread reads from exactly one 1KB bins row across all VPT elements.
    const float* __restrict__ brow = bins + (tid & (D_LAT - 1)) * NBINS;

    float s = 0.0f;
#pragma unroll
    for (int k = 0; k < VPT; ++k) {
        const int i = base + k * BLOCK;
        const float v = z[i];

        // Candidate nearest-bin index via uniform-spacing formula, clamped.
        float t = (v + 1.0f) * 127.5f;
        int j = (int)floorf(t + 0.5f);
        j = min(max(j, 0), NBINS - 1);

        // Refine with actual bin values; tie-break to LOWEST index (argmin semantics).
        int best = j;
        float bv = brow[j];
        float bd = fabsf(v - bv);
        if (j > 0) {
            float b0 = brow[j - 1];
            float d0 = fabsf(v - b0);
            if (d0 <= bd) { best = j - 1; bv = b0; bd = d0; } // <= : lower index wins tie
        }
        if (j + 1 < NBINS) {
            float b1 = brow[j + 1];
            float d1 = fabsf(v - b1);
            if (d1 < bd) { best = j + 1; bv = b1; bd = d1; } // strict < : lower index wins tie
        }

        out[1 + i] = bv;
        out[1 + N_ELEM + i] = (float)best;

        float diff = v - bv;
        s = fmaf(diff, diff, s);
    }

    // wave reduce, then 4-wave LDS combine -> one partial per block
#pragma unroll
    for (int off = 32; off > 0; off >>= 1) s += __shfl_down(s, off, 64);

    __shared__ float lds[BLOCK / 64];
    const int lane = tid & 63;
    const int wave = tid >> 6;
    if (lane == 0) lds[wave] = s;
    __syncthreads();
    if (tid == 0) {
        partial[blockIdx.x] = lds[0] + lds[1] + lds[2] + lds[3];
        // release: makes the partial store agent-visible before the flag
        __hip_atomic_store(&flags[blockIdx.x], FLAG_MAGIC,
                           __ATOMIC_RELEASE, __HIP_MEMORY_SCOPE_AGENT);
    }

    if (blockIdx.x != 0) return; // 1023 blocks exit immediately — no grid barrier

    // Block 0: each thread acquire-spins on its 4 flags, then fixed-tree reduce.
#pragma unroll
    for (int k = 0; k < GRID / BLOCK; ++k) {
        while (__hip_atomic_load(&flags[tid + k * BLOCK],
                                 __ATOMIC_ACQUIRE, __HIP_MEMORY_SCOPE_AGENT) != FLAG_MAGIC) {
            __builtin_amdgcn_s_sleep(2); // back off ~128 cycles between polls
        }
    }
    __syncthreads();

    float t = partial[tid] + partial[tid + 256] + partial[tid + 512] + partial[tid + 768];
#pragma unroll
    for (int off = 32; off > 0; off >>= 1) t += __shfl_down(t, off, 64);

    __shared__ float lds2[BLOCK / 64];
    if (lane == 0) lds2[wave] = t;
    __syncthreads();
    if (tid == 0) out[0] = 2.0f * (lds2[0] + lds2[1] + lds2[2] + lds2[3]) / (float)N_ELEM;
}

extern "C" void kernel_launch(void* const* d_in, const int* in_sizes, int n_in,
                              void* d_out, int out_size, void* d_ws, size_t ws_size,
                              hipStream_t stream) {
    const float* z = (const float*)d_in[0];
    const float* bins = (const float*)d_in[1];
    float* out = (float*)d_out;
    float* partial = (float*)d_ws;                        // 1024 floats
    unsigned int* flags = (unsigned int*)d_ws + GRID;     // 1024 flag words after partials

    fsq_fused<<<GRID, BLOCK, 0, stream>>>(z, bins, out, partial, flags);
}

// Round 4
// 67.841 us; speedup vs baseline: 2.6463x; 1.2966x over previous
//
#include <hip/hip_runtime.h>

// FSQ: z (4,16,256,64) fp32, bins (64,256) fp32 (uniform linspace(-1,1,256) per row).
// Outputs flat fp32: [loss(1), z_q(1048576), bin_indices_as_float(1048576)]
// loss = 2 * mean((z - zq)^2)   (commitment + BETA*codebook, BETA=1, identical forward)
//
// R1: 4 elems/thread, k*BLOCK stride (d = tid&63 per-thread constant -> one 1KB
//     bins row per thread), 1024 blocks + single-wave reduce kernel. 72.2 -> 68.3 us. BEST.
// R2: cooperative grid.sync() fusion. FAILED (179.5 us): grid sync ~107 us — 1024
//     blocks spinning device-scope atomics across 8 non-coherent XCD L2s.
// R3: single-launch release/acquire lookback. FAILED (88.0 us): agent-scope release
//     on gfx950 = per-block L2 writeback fence (non-coherent XCD L2s) -> 1024
//     writeback storms replace the ONE implicit flush a kernel boundary does free.
// R4: revert to R1. On CDNA4 the stream dependency between two launches IS the
//     cheapest cross-XCD sync for a 4KB reduction. Do not re-fuse.

#define N_ELEM (4 * 16 * 256 * 64) // 1048576
#define D_LAT 64
#define NBINS 256
#define BLOCK 256
#define VPT 4
#define CHUNK (BLOCK * VPT)   // 1024 elements per block
#define GRID (N_ELEM / CHUNK) // 1024

__global__ __launch_bounds__(BLOCK) void fsq_main(const float* __restrict__ z,
                                                  const float* __restrict__ bins,
                                                  float* __restrict__ out,
                                                  float* __restrict__ partial) {
    const int tid = threadIdx.x;
    const int base = blockIdx.x * CHUNK + tid;
    // CHUNK and BLOCK are multiples of 64, so d = (base + k*BLOCK) & 63 == tid & 63:
    // each thread reads from exactly one 1KB bins row across all VPT elements,
    // and every load/store instruction is perfectly lane-coalesced.
    const float* __restrict__ brow = bins + (tid & (D_LAT - 1)) * NBINS;

    float s = 0.0f;
#pragma unroll
    for (int k = 0; k < VPT; ++k) {
        const int i = base + k * BLOCK;
        const float v = z[i];

        // Candidate nearest-bin index via uniform-spacing formula, clamped.
        float t = (v + 1.0f) * 127.5f;
        int j = (int)floorf(t + 0.5f);
        j = min(max(j, 0), NBINS - 1);

        // Refine with actual bin values; tie-break to LOWEST index (argmin semantics).
        int best = j;
        float bv = brow[j];
        float bd = fabsf(v - bv);
        if (j > 0) {
            float b0 = brow[j - 1];
            float d0 = fabsf(v - b0);
            if (d0 <= bd) { best = j - 1; bv = b0; bd = d0; } // <= : lower index wins tie
        }
        if (j + 1 < NBINS) {
            float b1 = brow[j + 1];
            float d1 = fabsf(v - b1);
            if (d1 < bd) { best = j + 1; bv = b1; bd = d1; } // strict < : lower index wins tie
        }

        out[1 + i] = bv;
        out[1 + N_ELEM + i] = (float)best;

        float diff = v - bv;
        s = fmaf(diff, diff, s);
    }

    // wave reduce, then 4-wave LDS combine -> one partial per block
#pragma unroll
    for (int off = 32; off > 0; off >>= 1) s += __shfl_down(s, off, 64);

    __shared__ float lds[BLOCK / 64];
    const int lane = tid & 63;
    const int wave = tid >> 6;
    if (lane == 0) lds[wave] = s;
    __syncthreads();
    if (tid == 0) partial[blockIdx.x] = lds[0] + lds[1] + lds[2] + lds[3];
}

__global__ __launch_bounds__(64) void fsq_reduce(const float* __restrict__ partial,
                                                 float* __restrict__ out) {
    // single wave: 16 coalesced strided loads, butterfly reduce, no LDS/sync
    float s = 0.0f;
#pragma unroll
    for (int k = 0; k < GRID / 64; ++k) s += partial[threadIdx.x + k * 64];
#pragma unroll
    for (int off = 32; off > 0; off >>= 1) s += __shfl_down(s, off, 64);
    if (threadIdx.x == 0) out[0] = 2.0f * s / (float)N_ELEM; // (1 + BETA) * mean
}

extern "C" void kernel_launch(void* const* d_in, const int* in_sizes, int n_in,
                              void* d_out, int out_size, void* d_ws, size_t ws_size,
                              hipStream_t stream) {
    const float* z = (const float*)d_in[0];
    const float* bins = (const float*)d_in[1];
    float* out = (float*)d_out;
    float* partial = (float*)d_ws; // 1024 floats, fully written before read

    fsq_main<<<GRID, BLOCK, 0, stream>>>(z, bins, out, partial);
    fsq_reduce<<<1, 64, 0, stream>>>(partial, out);
}